// Round 4
// baseline (135.517 us; speedup 1.0000x reference)
//
#include <hip/hip_runtime.h>

// PointCrop2D: out[b,i,j,c] = in-bounds ? images[b, y-112+i, x-112+j, c] : -2.0f
// B=32, H=W=512, C=3, CROP=224, fill = (0-0.45)/0.225 = -2.0
//
// grid = (98, 32), block = 192 (3 waves); blockIdx.y = batch -> points fetch,
// clamps, column base, and realignment shift sh are wave-uniform (scalar).
//
// 8-float tiles: an output row is 672 floats = 84 groups of 8, so a per-thread
// 8-float (2x float4) tile NEVER crosses a row boundary -> one division, one
// row clamp, one bounds check and one realign chain per 32B of output.
// 98*192*8 = 150528 floats = one image, exact (no guard needed).
//
// Source-float coords: output float p of a row reads source float
// S = (x-112)*3 + p; valid col (0..510) <=> 0 <= S <= 1532.
// p % 8 == 0 ⇒ S ≡ colbase3 (mod 4), so A = S - sh (sh = colbase3 & 3) is a
// 16B-aligned float4 index. Fast path: 2-3 aligned nontemporal float4 loads +
// uniform-branch register realign. All traffic is single-use (the harness
// poison fill thrashes L2/L3 every iteration) -> nontemporal throughout.

#define B_N   32
#define H_N   512
#define W_N   512
#define C_N   3
#define CROP  224
#define DIA   112
#define FILLV (-2.0f)

typedef float f32x4 __attribute__((ext_vector_type(4)));

__global__ __launch_bounds__(192)
void PointCrop2D_27943057227941_kernel(const float* __restrict__ points,
                                       const float* __restrict__ images,
                                       float* __restrict__ out)
{
    const int ROWF = CROP * C_N;            // 672 floats per output row
    const int IMGF = CROP * ROWF;           // 150528 floats per output image

    const int b = blockIdx.y;               // uniform -> scalar path

    // points layout (B,3,3): x = points[b,0,0] -> b*9+0 ; y = points[b,1,0] -> b*9+3
    int xp = (int)points[b * 9 + 0];        // trunc == floor (values >= 0)
    int yp = (int)points[b * 9 + 3];
    int x  = min(max(xp, 1), W_N - 2);
    int y  = min(max(yp, 1), H_N - 2);
    int colbase3 = (x - DIA) * 3;           // uniform source-float column offset
    int rowbase  = y - DIA;                 // uniform first source row
    int sh       = colbase3 & 3;            // uniform realignment shift

    int t     = blockIdx.x * blockDim.x + threadIdx.x;  // [0, 18816), exact
    int pflat = t << 3;                     // first float of this thread's tile
    int i     = (int)((unsigned)pflat / (unsigned)ROWF); // single magic-mul div
    int p     = pflat - i * ROWF;           // [0,664], multiple of 8 (same row)

    int  r     = rowbase + i;               // source image row
    bool rowok = (unsigned)r <= (unsigned)(H_N - 2);    // row 511 is fill
    int  ra    = min(max(r, 0), H_N - 1);   // clamped for safe addressing

    const float* rowptr = images + ((size_t)b * H_N + (size_t)ra) * (W_N * C_N);

    int S = colbase3 + p;                   // source float index of element 0

    f32x4 v0, v1;

    if (rowok && (unsigned)S <= 1525u) {    // S+7 <= 1532: all 8 in-bounds
        int A = S - sh;                     // = S & ~3: 16B-aligned, A >= 0
        const f32x4* ap = reinterpret_cast<const f32x4*>(rowptr + A);
        f32x4 c0 = __builtin_nontemporal_load(ap);
        f32x4 c1 = __builtin_nontemporal_load(ap + 1);
        if (sh == 0) {                      // uniform branch
            v0 = c0; v1 = c1;
        } else {
            // chunk A+8..A+11 <= 1535: still inside this source row
            f32x4 c2 = __builtin_nontemporal_load(ap + 2);
            if (sh == 1) {
                v0 = (f32x4){c0.y, c0.z, c0.w, c1.x};
                v1 = (f32x4){c1.y, c1.z, c1.w, c2.x};
            } else if (sh == 2) {
                v0 = (f32x4){c0.z, c0.w, c1.x, c1.y};
                v1 = (f32x4){c1.z, c1.w, c2.x, c2.y};
            } else {
                v0 = (f32x4){c0.w, c1.x, c1.y, c1.z};
                v1 = (f32x4){c1.w, c2.x, c2.y, c2.z};
            }
        }
    } else {                                // boundary / fill lanes only
#pragma unroll
        for (int k = 0; k < 8; ++k) {
            int  sf = S + k;
            bool ok = rowok && ((unsigned)sf <= 1532u); // col in [0,510]
            int  sfa = min(max(sf, 0), W_N * C_N - 1);  // safe address
            float e = ok ? rowptr[sfa] : FILLV;
            if (k < 4) v0[k] = e; else v1[k - 4] = e;
        }
    }

    size_t og = (size_t)b * (IMGF / 4) + ((size_t)pflat >> 2);
    __builtin_nontemporal_store(v0, reinterpret_cast<f32x4*>(out) + og);
    __builtin_nontemporal_store(v1, reinterpret_cast<f32x4*>(out) + og + 1);
}

extern "C" void kernel_launch(void* const* d_in, const int* in_sizes, int n_in,
                              void* d_out, int out_size, void* d_ws, size_t ws_size,
                              hipStream_t stream) {
    const float* points = (const float*)d_in[0];
    const float* images = (const float*)d_in[1];
    float* out = (float*)d_out;

    // 98 blocks * 192 threads * 8 floats = 150528 floats = one image, exact
    dim3 grid(98, B_N);
    PointCrop2D_27943057227941_kernel<<<grid, dim3(192), 0, stream>>>(points, images, out);
}

// Round 5
// 132.852 us; speedup vs baseline: 1.0201x; 1.0201x over previous
//
#include <hip/hip_runtime.h>

// PointCrop2D: out[b,i,j,c] = in-bounds ? images[b, y-112+i, x-112+j, c] : -2.0f
// B=32, H=W=512, C=3, CROP=224, fill = (0-0.45)/0.225 = -2.0
//
// REVERT to the Round-3 configuration (measured 131.6 us, session best).
// Round-4 post-mortem: 8-float/thread tiles (block=192, 9.4K waves) regressed
// +2.5 us — the kernel slice is latency/TLP-bound; halving wave count cut
// latency hiding more than the per-thread ILP gained. Keep 4-float tiles,
// 256-thread blocks, 18.8K waves.
//
// grid = (147, 32), block = 256; blockIdx.y = batch -> points fetch, clamps,
// column base, and the realignment shift sh are all wave-uniform (scalar).
//
// Source-float coords: output float p of a row reads source float
// S = (x-112)*3 + p; valid col (0..510) <=> 0 <= S <= 1532.
// Since p % 4 == 0, A = S & ~3 = S - sh with sh = colbase3 & 3 uniform.
// Fast path: 1-2 16B-ALIGNED nontemporal float4 loads + uniform register
// realign. All traffic is single-use (the harness poison fill thrashes
// L2/L3 every iteration) -> nontemporal loads and stores throughout.

#define B_N   32
#define H_N   512
#define W_N   512
#define C_N   3
#define CROP  224
#define DIA   112
#define FILLV (-2.0f)

typedef float f32x4 __attribute__((ext_vector_type(4)));

__global__ __launch_bounds__(256)
void PointCrop2D_27943057227941_kernel(const float* __restrict__ points,
                                       const float* __restrict__ images,
                                       float* __restrict__ out)
{
    const int ROWF = CROP * C_N;            // 672 floats per output row
    const int IMGF = CROP * ROWF;           // 150528 floats per output image

    const int b = blockIdx.y;               // uniform -> scalar path

    // points layout (B,3,3): x = points[b,0,0] -> b*9+0 ; y = points[b,1,0] -> b*9+3
    int xp = (int)points[b * 9 + 0];        // trunc == floor (values >= 0)
    int yp = (int)points[b * 9 + 3];
    int x  = min(max(xp, 1), W_N - 2);
    int y  = min(max(yp, 1), H_N - 2);
    int colbase3 = (x - DIA) * 3;           // uniform source-float column offset
    int rowbase  = y - DIA;                 // uniform first source row
    int sh       = colbase3 & 3;            // uniform realignment shift

    int t     = blockIdx.x * blockDim.x + threadIdx.x;  // [0, 37632), exact
    int pflat = t << 2;                     // float index within this image
    int i     = (int)((unsigned)pflat / (unsigned)ROWF); // single magic-mul div
    int p     = pflat - i * ROWF;           // [0,672), multiple of 4

    int  r     = rowbase + i;               // source image row
    bool rowok = (unsigned)r <= (unsigned)(H_N - 2);    // row 511 is fill
    int  ra    = min(max(r, 0), H_N - 1);   // clamped for safe addressing

    const float* rowptr = images + ((size_t)b * H_N + (size_t)ra) * (W_N * C_N);

    int S = colbase3 + p;                   // source float index of element 0

    f32x4 v;

    if (rowok && (unsigned)S <= 1529u) {    // S+3 <= 1532: all 4 in-bounds
        int A = S - sh;                     // = S & ~3: 16B-aligned float4 index
        const f32x4* ap = reinterpret_cast<const f32x4*>(rowptr + A);
        f32x4 lo = __builtin_nontemporal_load(ap);
        if (sh == 0) {                      // uniform branch
            v = lo;
        } else {
            // hi spans A+4..A+7 <= S-1+7 <= 1535 : still inside this row
            f32x4 hi = __builtin_nontemporal_load(ap + 1);
            if (sh == 1)      v = (f32x4){lo.y, lo.z, lo.w, hi.x};
            else if (sh == 2) v = (f32x4){lo.z, lo.w, hi.x, hi.y};
            else              v = (f32x4){lo.w, hi.x, hi.y, hi.z};
        }
    } else {                                // boundary / fill lanes only
#pragma unroll
        for (int k = 0; k < 4; ++k) {
            int  sf = S + k;
            bool ok = rowok && ((unsigned)sf <= 1532u); // col in [0,510]
            int  sfa = min(max(sf, 0), W_N * C_N - 1);  // safe address
            v[k] = ok ? rowptr[sfa] : FILLV;
        }
    }

    size_t og = ((size_t)b * IMGF + (size_t)pflat) >> 2;
    __builtin_nontemporal_store(v, reinterpret_cast<f32x4*>(out) + og);
}

extern "C" void kernel_launch(void* const* d_in, const int* in_sizes, int n_in,
                              void* d_out, int out_size, void* d_ws, size_t ws_size,
                              hipStream_t stream) {
    const float* points = (const float*)d_in[0];
    const float* images = (const float*)d_in[1];
    float* out = (float*)d_out;

    // 147 blocks * 256 threads * 4 floats = 150528 floats = one image, exact
    dim3 grid(147, B_N);
    PointCrop2D_27943057227941_kernel<<<grid, dim3(256), 0, stream>>>(points, images, out);
}